// Round 1
// baseline (250.482 us; speedup 1.0000x reference)
//
#include <hip/hip_runtime.h>

// Problem constants (fixed-shape harness)
constexpr int N_NODES = 10000;
constexpr int N_EDGES = 320000;
constexpr int IN_CH   = 128;
constexpr int HID     = 64;
constexpr int HEADS   = 4;
constexpr int OUT_CH  = 64;
constexpr int F1      = HEADS * HID;   // 256
constexpr float NEG_SLOPE = 0.2f;

// ---------------- CSR build ----------------

__global__ void k_zero2(int* __restrict__ counts, int* __restrict__ cursor) {
    int i = blockIdx.x * 256 + threadIdx.x;
    if (i < N_NODES) { counts[i] = 0; cursor[i] = 0; }
}

__global__ void k_count(const int* __restrict__ dst, int* __restrict__ counts) {
    int e = blockIdx.x * 256 + threadIdx.x;
    if (e < N_EDGES) atomicAdd(&counts[dst[e]], 1);
}

__global__ __launch_bounds__(1024) void k_scan(const int* __restrict__ counts,
                                               int* __restrict__ row_ptr) {
    __shared__ int s[1024];
    int tid = threadIdx.x;
    int carry = 0;
    for (int base = 0; base < N_NODES; base += 1024) {
        int i = base + tid;
        int v = (i < N_NODES) ? counts[i] : 0;
        s[tid] = v;
        __syncthreads();
        for (int off = 1; off < 1024; off <<= 1) {
            int t = (tid >= off) ? s[tid - off] : 0;
            __syncthreads();
            s[tid] += t;
            __syncthreads();
        }
        if (i < N_NODES) row_ptr[i] = carry + s[tid] - v;  // exclusive
        int total = s[1023];
        __syncthreads();
        carry += total;
    }
    if (tid == 0) row_ptr[N_NODES] = carry;
}

__global__ void k_fill(const int* __restrict__ dst, const int* __restrict__ row_ptr,
                       int* __restrict__ cursor, int* __restrict__ edge_ids) {
    int e = blockIdx.x * 256 + threadIdx.x;
    if (e >= N_EDGES) return;
    int d = dst[e];
    int pos = row_ptr[d] + atomicAdd(&cursor[d], 1);
    edge_ids[pos] = e;
}

// ---------------- tiny precompute: de[h] = dot(We_h, a_edge_h) ----------------

__global__ void k_de(const float* __restrict__ We1, const float* __restrict__ ae1,
                     const float* __restrict__ We2, const float* __restrict__ ae2,
                     float* __restrict__ de) {
    int t = threadIdx.x;
    if (t < HEADS) {
        float s = 0.f;
        for (int c = 0; c < HID; ++c) s = fmaf(We1[t * HID + c], ae1[t * HID + c], s);
        de[t] = s;
    } else if (t == HEADS) {
        float s = 0.f;
        for (int c = 0; c < OUT_CH; ++c) s = fmaf(We2[c], ae2[c], s);
        de[HEADS] = s;
    }
}

// ---------------- GEMM 1: xh1 = x @ W1   [10000,128]x[128,256] ----------------

__global__ __launch_bounds__(256) void k_gemm1(const float* __restrict__ x,
                                               const float* __restrict__ W,
                                               float* __restrict__ xh) {
    __shared__ float xs[16 * 128];
    int tid = threadIdx.x;
    int row0 = blockIdx.x * 16;
    const float4* xg = (const float4*)(x + (size_t)row0 * IN_CH);
    float4* xs4 = (float4*)xs;
    xs4[tid]       = xg[tid];
    xs4[tid + 256] = xg[tid + 256];
    __syncthreads();
    float acc[16];
    #pragma unroll
    for (int m = 0; m < 16; ++m) acc[m] = 0.f;
    int col = tid;  // 0..255
    for (int k = 0; k < IN_CH; ++k) {
        float w = W[k * F1 + col];
        #pragma unroll
        for (int m = 0; m < 16; ++m) acc[m] = fmaf(xs[m * 128 + k], w, acc[m]);
    }
    #pragma unroll
    for (int m = 0; m < 16; ++m) xh[(size_t)(row0 + m) * F1 + col] = acc[m];
}

// ---------------- per-node attention dots, layer 1 ----------------

__global__ void k_dots1(const float* __restrict__ xh, const float* __restrict__ a_src,
                        const float* __restrict__ a_dst,
                        float* __restrict__ als, float* __restrict__ ald) {
    int t = blockIdx.x * 256 + threadIdx.x;
    if (t >= N_NODES * HEADS) return;
    int n = t >> 2, h = t & 3;
    const float* xr = xh + (size_t)n * F1 + h * HID;
    const float* as = a_src + h * HID;
    const float* ad = a_dst + h * HID;
    float s = 0.f, d = 0.f;
    for (int c = 0; c < HID; ++c) {
        float v = xr[c];
        s = fmaf(v, as[c], s);
        d = fmaf(v, ad[c], d);
    }
    als[t] = s;
    ald[t] = d;
}

// ---------------- fused layer-1 aggregation + softmax + bias + ELU ----------------
// One 64-lane wave per node; lane owns 4 consecutive channels (head = lane/16).

__global__ __launch_bounds__(256) void k_agg1(
        const float* __restrict__ xh, const float* __restrict__ als,
        const float* __restrict__ ald, const float* __restrict__ ew,
        const int* __restrict__ src, const int* __restrict__ row_ptr,
        const int* __restrict__ edge_ids, const float* __restrict__ de,
        const float* __restrict__ bias, float* __restrict__ hout) {
    int node = blockIdx.x * 4 + (threadIdx.x >> 6);
    if (node >= N_NODES) return;
    int lane = threadIdx.x & 63;
    int h = lane >> 4;
    int c4 = lane << 2;  // 0..252
    float aldv = ald[node * HEADS + h];
    float deh = de[h];
    float4 acc = make_float4(0.f, 0.f, 0.f, 0.f);
    float den = 0.f;
    int beg = row_ptr[node], end = row_ptr[node + 1];
    for (int i = beg; i < end; ++i) {
        int e = edge_ids[i];
        int s = src[e];
        float w = ew[e];
        float a = als[s * HEADS + h] + aldv + w * deh;
        a = a > 0.f ? a : NEG_SLOPE * a;
        float ex = expf(a);
        den += ex;
        float4 xv = *(const float4*)(xh + (size_t)s * F1 + c4);
        acc.x = fmaf(ex, xv.x, acc.x);
        acc.y = fmaf(ex, xv.y, acc.y);
        acc.z = fmaf(ex, xv.z, acc.z);
        acc.w = fmaf(ex, xv.w, acc.w);
    }
    float inv = 1.f / (den + 1e-16f);
    float4 o;
    o.x = acc.x * inv + bias[c4 + 0];
    o.y = acc.y * inv + bias[c4 + 1];
    o.z = acc.z * inv + bias[c4 + 2];
    o.w = acc.w * inv + bias[c4 + 3];
    // ELU
    o.x = o.x > 0.f ? o.x : expm1f(o.x);
    o.y = o.y > 0.f ? o.y : expm1f(o.y);
    o.z = o.z > 0.f ? o.z : expm1f(o.z);
    o.w = o.w > 0.f ? o.w : expm1f(o.w);
    *(float4*)(hout + (size_t)node * F1 + c4) = o;
}

// ---------------- GEMM 2: xh2 = h @ W2   [10000,256]x[256,64] ----------------

__global__ __launch_bounds__(256) void k_gemm2(const float* __restrict__ hin,
                                               const float* __restrict__ W,
                                               float* __restrict__ xh2) {
    __shared__ float hs[16 * 256];
    int tid = threadIdx.x;
    int row0 = blockIdx.x * 16;
    const float4* hg = (const float4*)(hin + (size_t)row0 * F1);
    float4* hs4 = (float4*)hs;
    #pragma unroll
    for (int j = 0; j < 4; ++j) hs4[tid + j * 256] = hg[tid + j * 256];
    __syncthreads();
    int col = tid & 63;
    int rq = tid >> 6;  // 0..3
    float acc[4] = {0.f, 0.f, 0.f, 0.f};
    for (int k = 0; k < F1; ++k) {
        float w = W[k * OUT_CH + col];
        #pragma unroll
        for (int m = 0; m < 4; ++m) acc[m] = fmaf(hs[(rq * 4 + m) * 256 + k], w, acc[m]);
    }
    #pragma unroll
    for (int m = 0; m < 4; ++m) xh2[(size_t)(row0 + rq * 4 + m) * OUT_CH + col] = acc[m];
}

// ---------------- per-node attention dots, layer 2 (H=1) ----------------

__global__ void k_dots2(const float* __restrict__ xh2, const float* __restrict__ a_src,
                        const float* __restrict__ a_dst,
                        float* __restrict__ als, float* __restrict__ ald) {
    int n = blockIdx.x * 256 + threadIdx.x;
    if (n >= N_NODES) return;
    const float* xr = xh2 + (size_t)n * OUT_CH;
    float s = 0.f, d = 0.f;
    for (int c = 0; c < OUT_CH; ++c) {
        float v = xr[c];
        s = fmaf(v, a_src[c], s);
        d = fmaf(v, a_dst[c], d);
    }
    als[n] = s;
    ald[n] = d;
}

// ---------------- fused layer-2 aggregation + bias ----------------
// One wave per node; lane owns 1 channel.

__global__ __launch_bounds__(256) void k_agg2(
        const float* __restrict__ xh2, const float* __restrict__ als,
        const float* __restrict__ ald, const float* __restrict__ ew,
        const int* __restrict__ src, const int* __restrict__ row_ptr,
        const int* __restrict__ edge_ids, const float* __restrict__ de,
        const float* __restrict__ bias, float* __restrict__ out) {
    int node = blockIdx.x * 4 + (threadIdx.x >> 6);
    if (node >= N_NODES) return;
    int lane = threadIdx.x & 63;
    float aldv = ald[node];
    float dee = de[HEADS];  // de2
    float acc = 0.f, den = 0.f;
    int beg = row_ptr[node], end = row_ptr[node + 1];
    for (int i = beg; i < end; ++i) {
        int e = edge_ids[i];
        int s = src[e];
        float w = ew[e];
        float a = als[s] + aldv + w * dee;
        a = a > 0.f ? a : NEG_SLOPE * a;
        float ex = expf(a);
        den += ex;
        acc = fmaf(ex, xh2[(size_t)s * OUT_CH + lane], acc);
    }
    out[(size_t)node * OUT_CH + lane] = acc / (den + 1e-16f) + bias[lane];
}

// ---------------- launch ----------------

extern "C" void kernel_launch(void* const* d_in, const int* in_sizes, int n_in,
                              void* d_out, int out_size, void* d_ws, size_t ws_size,
                              hipStream_t stream) {
    const float* x       = (const float*)d_in[0];
    const float* ew      = (const float*)d_in[1];
    const float* W1      = (const float*)d_in[2];
    const float* a_src1  = (const float*)d_in[3];
    const float* a_dst1  = (const float*)d_in[4];
    const float* a_edge1 = (const float*)d_in[5];
    const float* We1     = (const float*)d_in[6];
    const float* b1      = (const float*)d_in[7];
    const float* W2      = (const float*)d_in[8];
    const float* a_src2  = (const float*)d_in[9];
    const float* a_dst2  = (const float*)d_in[10];
    const float* a_edge2 = (const float*)d_in[11];
    const float* We2     = (const float*)d_in[12];
    const float* b2      = (const float*)d_in[13];
    const int*   eidx    = (const int*)d_in[14];
    const int* esrc = eidx;
    const int* edst = eidx + N_EDGES;
    float* out = (float*)d_out;

    // workspace layout (bytes, 256-aligned chunks)
    char* p = (char*)d_ws;
    auto alloc = [&](size_t bytes) {
        char* r = p;
        p += (bytes + 255) & ~(size_t)255;
        return r;
    };
    float* xh1   = (float*)alloc((size_t)N_NODES * F1 * 4);      // 10.24 MB
    float* h1    = (float*)alloc((size_t)N_NODES * F1 * 4);      // 10.24 MB
    float* xh2   = (float*)alloc((size_t)N_NODES * OUT_CH * 4);  // 2.56 MB
    float* als1  = (float*)alloc((size_t)N_NODES * HEADS * 4);
    float* ald1  = (float*)alloc((size_t)N_NODES * HEADS * 4);
    float* als2  = (float*)alloc((size_t)N_NODES * 4);
    float* ald2  = (float*)alloc((size_t)N_NODES * 4);
    float* de    = (float*)alloc(8 * 4);
    int* counts  = (int*)alloc((size_t)N_NODES * 4);
    int* cursor  = (int*)alloc((size_t)N_NODES * 4);
    int* row_ptr = (int*)alloc((size_t)(N_NODES + 1) * 4);
    int* edge_ids= (int*)alloc((size_t)N_EDGES * 4);

    // CSR build
    k_zero2<<<(N_NODES + 255) / 256, 256, 0, stream>>>(counts, cursor);
    k_count<<<N_EDGES / 256, 256, 0, stream>>>(edst, counts);
    k_scan<<<1, 1024, 0, stream>>>(counts, row_ptr);
    k_fill<<<N_EDGES / 256, 256, 0, stream>>>(edst, row_ptr, cursor, edge_ids);

    // scalar precompute
    k_de<<<1, 64, 0, stream>>>(We1, a_edge1, We2, a_edge2, de);

    // layer 1
    k_gemm1<<<N_NODES / 16, 256, 0, stream>>>(x, W1, xh1);
    k_dots1<<<(N_NODES * HEADS + 255) / 256, 256, 0, stream>>>(xh1, a_src1, a_dst1, als1, ald1);
    k_agg1<<<N_NODES / 4, 256, 0, stream>>>(xh1, als1, ald1, ew, esrc, row_ptr,
                                            edge_ids, de, b1, h1);

    // layer 2
    k_gemm2<<<N_NODES / 16, 256, 0, stream>>>(h1, W2, xh2);
    k_dots2<<<(N_NODES + 255) / 256, 256, 0, stream>>>(xh2, a_src2, a_dst2, als2, ald2);
    k_agg2<<<N_NODES / 4, 256, 0, stream>>>(xh2, als2, ald2, ew, esrc, row_ptr,
                                            edge_ids, de, b2, out);
}

// Round 2
// 179.532 us; speedup vs baseline: 1.3952x; 1.3952x over previous
//
#include <hip/hip_runtime.h>

constexpr int N_NODES = 10000;
constexpr int N_EDGES = 320000;
constexpr int IN_CH   = 128;
constexpr int HID     = 64;
constexpr int HEADS   = 4;
constexpr int OUT_CH  = 64;
constexpr int F1      = HEADS * HID;   // 256
constexpr float NEG_SLOPE = 0.2f;

// ---------------- CSR build ----------------

__global__ void k_zero2(int* __restrict__ counts, int* __restrict__ cursor) {
    int i = blockIdx.x * 256 + threadIdx.x;
    if (i < N_NODES) { counts[i] = 0; cursor[i] = 0; }
}

__global__ void k_count(const int* __restrict__ dst, int* __restrict__ counts) {
    int e = blockIdx.x * 256 + threadIdx.x;
    if (e < N_EDGES) atomicAdd(&counts[dst[e]], 1);
}

// wave-shuffle based scan: 10 chunks x 3 syncs
__global__ __launch_bounds__(1024) void k_scan(const int* __restrict__ counts,
                                               int* __restrict__ row_ptr) {
    __shared__ int wsum[16];
    __shared__ int s_carry;
    int tid = threadIdx.x, lane = tid & 63, w = tid >> 6;
    if (tid == 0) s_carry = 0;
    __syncthreads();
    for (int base = 0; base < N_NODES; base += 1024) {
        int i = base + tid;
        int v = (i < N_NODES) ? counts[i] : 0;
        int x = v;
        #pragma unroll
        for (int off = 1; off < 64; off <<= 1) {
            int t = __shfl_up(x, off, 64);
            if (lane >= off) x += t;
        }
        if (lane == 63) wsum[w] = x;
        __syncthreads();                                   // A
        if (w == 0 && lane < 16) {
            int y = wsum[lane];
            #pragma unroll
            for (int off = 1; off < 16; off <<= 1) {
                int u = __shfl_up(y, off, 64);
                if (lane >= off) y += u;
            }
            wsum[lane] = y;                                // inclusive
        }
        __syncthreads();                                   // B
        int carry = s_carry;
        int woff = w ? wsum[w - 1] : 0;
        if (i < N_NODES) row_ptr[i] = carry + woff + x - v; // exclusive
        int total = wsum[15];
        __syncthreads();                                   // C
        if (tid == 0) s_carry = carry + total;
    }
    if (tid == 0) row_ptr[N_NODES] = s_carry;
}

__global__ void k_fill(const int* __restrict__ dst, const int* __restrict__ row_ptr,
                       int* __restrict__ cursor, int* __restrict__ edge_ids) {
    int e = blockIdx.x * 256 + threadIdx.x;
    if (e >= N_EDGES) return;
    int d = dst[e];
    int pos = row_ptr[d] + atomicAdd(&cursor[d], 1);
    edge_ids[pos] = e;
}

// ---------------- de[h] = dot(We_h, a_edge_h) ----------------

__global__ void k_de(const float* __restrict__ We1, const float* __restrict__ ae1,
                     const float* __restrict__ We2, const float* __restrict__ ae2,
                     float* __restrict__ de) {
    int t = threadIdx.x;
    if (t < HEADS) {
        float s = 0.f;
        for (int c = 0; c < HID; ++c) s = fmaf(We1[t * HID + c], ae1[t * HID + c], s);
        de[t] = s;
    } else if (t == HEADS) {
        float s = 0.f;
        for (int c = 0; c < OUT_CH; ++c) s = fmaf(We2[c], ae2[c], s);
        de[HEADS] = s;
    }
}

// ---------------- GEMM1 + fused src/dst dots ----------------
// [10000,128] @ [128,256]; BM=32, 256 thr: wave w = rows w*8..w*8+7, lane -> 4 cols.

__global__ __launch_bounds__(256) void k_gemm1(const float* __restrict__ x,
                                               const float* __restrict__ W,
                                               const float* __restrict__ a_src,
                                               const float* __restrict__ a_dst,
                                               float* __restrict__ xh,
                                               float* __restrict__ als,
                                               float* __restrict__ ald) {
    __shared__ float xs[32 * IN_CH];                       // 16 KB
    int tid = threadIdx.x;
    int row0 = blockIdx.x * 32;
    int nrows = N_NODES - row0; if (nrows > 32) nrows = 32;
    float4* xs4 = (float4*)xs;
    const float4* xg = (const float4*)(x + (size_t)row0 * IN_CH);
    #pragma unroll
    for (int j = 0; j < 4; ++j) {
        int idx = tid + j * 256;                           // f4 idx; row = idx>>5
        if ((idx >> 5) < nrows) xs4[idx] = xg[idx];
    }
    __syncthreads();
    int wv = tid >> 6;
    int lane = tid & 63;
    int col = lane * 4;
    float acc[8][4];
    #pragma unroll
    for (int m = 0; m < 8; ++m)
        #pragma unroll
        for (int j = 0; j < 4; ++j) acc[m][j] = 0.f;

    for (int k = 0; k < IN_CH; k += 4) {
        float4 w0 = *(const float4*)(W + (size_t)(k + 0) * F1 + col);
        float4 w1 = *(const float4*)(W + (size_t)(k + 1) * F1 + col);
        float4 w2 = *(const float4*)(W + (size_t)(k + 2) * F1 + col);
        float4 w3 = *(const float4*)(W + (size_t)(k + 3) * F1 + col);
        #pragma unroll
        for (int m = 0; m < 8; ++m) {
            float4 xv = *(const float4*)(xs + (wv * 8 + m) * IN_CH + k);
            acc[m][0] = fmaf(xv.x, w0.x, fmaf(xv.y, w1.x, fmaf(xv.z, w2.x, fmaf(xv.w, w3.x, acc[m][0]))));
            acc[m][1] = fmaf(xv.x, w0.y, fmaf(xv.y, w1.y, fmaf(xv.z, w2.y, fmaf(xv.w, w3.y, acc[m][1]))));
            acc[m][2] = fmaf(xv.x, w0.z, fmaf(xv.y, w1.z, fmaf(xv.z, w2.z, fmaf(xv.w, w3.z, acc[m][2]))));
            acc[m][3] = fmaf(xv.x, w0.w, fmaf(xv.y, w1.w, fmaf(xv.z, w2.w, fmaf(xv.w, w3.w, acc[m][3]))));
        }
    }
    int h = lane >> 4;
    float4 asv = *(const float4*)(a_src + h * HID + (lane & 15) * 4);
    float4 adv = *(const float4*)(a_dst + h * HID + (lane & 15) * 4);
    #pragma unroll
    for (int m = 0; m < 8; ++m) {
        int row = wv * 8 + m;
        if (row < nrows) *(float4*)(xh + (size_t)(row0 + row) * F1 + col) = *(float4*)acc[m];
        float s = acc[m][0] * asv.x + acc[m][1] * asv.y + acc[m][2] * asv.z + acc[m][3] * asv.w;
        float d = acc[m][0] * adv.x + acc[m][1] * adv.y + acc[m][2] * adv.z + acc[m][3] * adv.w;
        #pragma unroll
        for (int off = 1; off < 16; off <<= 1) {
            s += __shfl_xor(s, off, 64);
            d += __shfl_xor(d, off, 64);
        }
        if ((lane & 15) == 0 && row < nrows) {
            als[(size_t)(row0 + row) * HEADS + h] = s;
            ald[(size_t)(row0 + row) * HEADS + h] = d;
        }
    }
}

// ---------------- per-edge alpha, layer 1 (CSR order) ----------------

__global__ void k_alpha1(const int* __restrict__ edge_ids, const int* __restrict__ src,
                         const int* __restrict__ dst, const float* __restrict__ ew,
                         const float* __restrict__ als, const float* __restrict__ ald,
                         const float* __restrict__ de,
                         float* __restrict__ exs, int* __restrict__ srcs) {
    int i = blockIdx.x * 256 + threadIdx.x;
    if (i >= N_EDGES) return;
    int e = edge_ids[i];
    int s = src[e], d = dst[e];
    float w = ew[e];
    float4 as = *(const float4*)(als + (size_t)s * HEADS);
    float4 ad = *(const float4*)(ald + (size_t)d * HEADS);
    float4 dev = *(const float4*)de;
    float4 a;
    a.x = as.x + ad.x + w * dev.x;
    a.y = as.y + ad.y + w * dev.y;
    a.z = as.z + ad.z + w * dev.z;
    a.w = as.w + ad.w + w * dev.w;
    a.x = a.x > 0.f ? a.x : NEG_SLOPE * a.x;
    a.y = a.y > 0.f ? a.y : NEG_SLOPE * a.y;
    a.z = a.z > 0.f ? a.z : NEG_SLOPE * a.z;
    a.w = a.w > 0.f ? a.w : NEG_SLOPE * a.w;
    a.x = __expf(a.x); a.y = __expf(a.y); a.z = __expf(a.z); a.w = __expf(a.w);
    *(float4*)(exs + (size_t)i * 4) = a;
    srcs[i] = s;
}

// ---------------- fused layer-1 aggregation (+softmax norm + bias + ELU) --------
// wave per node, lane -> 4 channels, unroll 4 with independent gathers

__global__ __launch_bounds__(256) void k_agg1(
        const float* __restrict__ xh, const float* __restrict__ exs,
        const int* __restrict__ srcs, const int* __restrict__ row_ptr,
        const float* __restrict__ bias, float* __restrict__ hout) {
    int node = blockIdx.x * 4 + (threadIdx.x >> 6);
    int lane = threadIdx.x & 63;
    int h = lane >> 4;
    int c4 = lane << 2;
    int beg = row_ptr[node], end = row_ptr[node + 1];
    float4 acc = make_float4(0.f, 0.f, 0.f, 0.f);
    float den = 0.f;
    int i = beg;
    for (; i + 4 <= end; i += 4) {
        int s0 = srcs[i + 0], s1 = srcs[i + 1], s2 = srcs[i + 2], s3 = srcs[i + 3];
        float e0 = exs[(size_t)(i + 0) * 4 + h];
        float e1 = exs[(size_t)(i + 1) * 4 + h];
        float e2 = exs[(size_t)(i + 2) * 4 + h];
        float e3 = exs[(size_t)(i + 3) * 4 + h];
        float4 x0 = *(const float4*)(xh + (size_t)s0 * F1 + c4);
        float4 x1 = *(const float4*)(xh + (size_t)s1 * F1 + c4);
        float4 x2 = *(const float4*)(xh + (size_t)s2 * F1 + c4);
        float4 x3 = *(const float4*)(xh + (size_t)s3 * F1 + c4);
        den += (e0 + e1) + (e2 + e3);
        acc.x = fmaf(e0, x0.x, fmaf(e1, x1.x, fmaf(e2, x2.x, fmaf(e3, x3.x, acc.x))));
        acc.y = fmaf(e0, x0.y, fmaf(e1, x1.y, fmaf(e2, x2.y, fmaf(e3, x3.y, acc.y))));
        acc.z = fmaf(e0, x0.z, fmaf(e1, x1.z, fmaf(e2, x2.z, fmaf(e3, x3.z, acc.z))));
        acc.w = fmaf(e0, x0.w, fmaf(e1, x1.w, fmaf(e2, x2.w, fmaf(e3, x3.w, acc.w))));
    }
    for (; i < end; ++i) {
        int s = srcs[i];
        float e0 = exs[(size_t)i * 4 + h];
        float4 xv = *(const float4*)(xh + (size_t)s * F1 + c4);
        den += e0;
        acc.x = fmaf(e0, xv.x, acc.x);
        acc.y = fmaf(e0, xv.y, acc.y);
        acc.z = fmaf(e0, xv.z, acc.z);
        acc.w = fmaf(e0, xv.w, acc.w);
    }
    float inv = 1.f / (den + 1e-16f);
    float4 o;
    o.x = fmaf(acc.x, inv, bias[c4 + 0]);
    o.y = fmaf(acc.y, inv, bias[c4 + 1]);
    o.z = fmaf(acc.z, inv, bias[c4 + 2]);
    o.w = fmaf(acc.w, inv, bias[c4 + 3]);
    o.x = o.x > 0.f ? o.x : expm1f(o.x);
    o.y = o.y > 0.f ? o.y : expm1f(o.y);
    o.z = o.z > 0.f ? o.z : expm1f(o.z);
    o.w = o.w > 0.f ? o.w : expm1f(o.w);
    *(float4*)(hout + (size_t)node * F1 + c4) = o;
}

// ---------------- GEMM2 + fused dots2 ----------------
// [10000,256] @ [256,64]; BM=32, thread tile 2 rows x 4 cols.

__global__ __launch_bounds__(256) void k_gemm2(const float* __restrict__ hin,
                                               const float* __restrict__ W,
                                               const float* __restrict__ a_src,
                                               const float* __restrict__ a_dst,
                                               float* __restrict__ xh2,
                                               float* __restrict__ als,
                                               float* __restrict__ ald) {
    __shared__ float hs[32 * F1];                          // 32 KB
    int tid = threadIdx.x;
    int row0 = blockIdx.x * 32;
    int nrows = N_NODES - row0; if (nrows > 32) nrows = 32;
    float4* hs4 = (float4*)hs;
    const float4* hg = (const float4*)(hin + (size_t)row0 * F1);
    #pragma unroll
    for (int j = 0; j < 8; ++j) {
        int idx = tid + j * 256;                           // row = idx>>6
        if ((idx >> 6) < nrows) hs4[idx] = hg[idx];
    }
    __syncthreads();
    int rowg = tid >> 4;                                   // 0..15 -> rows rowg*2..+1
    int col = (tid & 15) * 4;
    float acc[2][4];
    #pragma unroll
    for (int m = 0; m < 2; ++m)
        #pragma unroll
        for (int j = 0; j < 4; ++j) acc[m][j] = 0.f;

    for (int k = 0; k < F1; k += 4) {
        float4 w0 = *(const float4*)(W + (size_t)(k + 0) * OUT_CH + col);
        float4 w1 = *(const float4*)(W + (size_t)(k + 1) * OUT_CH + col);
        float4 w2 = *(const float4*)(W + (size_t)(k + 2) * OUT_CH + col);
        float4 w3 = *(const float4*)(W + (size_t)(k + 3) * OUT_CH + col);
        #pragma unroll
        for (int m = 0; m < 2; ++m) {
            float4 xv = *(const float4*)(hs + (rowg * 2 + m) * F1 + k);
            acc[m][0] = fmaf(xv.x, w0.x, fmaf(xv.y, w1.x, fmaf(xv.z, w2.x, fmaf(xv.w, w3.x, acc[m][0]))));
            acc[m][1] = fmaf(xv.x, w0.y, fmaf(xv.y, w1.y, fmaf(xv.z, w2.y, fmaf(xv.w, w3.y, acc[m][1]))));
            acc[m][2] = fmaf(xv.x, w0.z, fmaf(xv.y, w1.z, fmaf(xv.z, w2.z, fmaf(xv.w, w3.z, acc[m][2]))));
            acc[m][3] = fmaf(xv.x, w0.w, fmaf(xv.y, w1.w, fmaf(xv.z, w2.w, fmaf(xv.w, w3.w, acc[m][3]))));
        }
    }
    int lane = tid & 63;
    float4 asv = *(const float4*)(a_src + col);
    float4 adv = *(const float4*)(a_dst + col);
    #pragma unroll
    for (int m = 0; m < 2; ++m) {
        int row = rowg * 2 + m;
        if (row < nrows) *(float4*)(xh2 + (size_t)(row0 + row) * OUT_CH + col) = *(float4*)acc[m];
        float s = acc[m][0] * asv.x + acc[m][1] * asv.y + acc[m][2] * asv.z + acc[m][3] * asv.w;
        float d = acc[m][0] * adv.x + acc[m][1] * adv.y + acc[m][2] * adv.z + acc[m][3] * adv.w;
        #pragma unroll
        for (int off = 1; off < 16; off <<= 1) {
            s += __shfl_xor(s, off, 64);
            d += __shfl_xor(d, off, 64);
        }
        if ((lane & 15) == 0 && row < nrows) {
            als[row0 + row] = s;
            ald[row0 + row] = d;
        }
    }
}

// ---------------- per-edge alpha, layer 2 ----------------

__global__ void k_alpha2(const int* __restrict__ edge_ids, const int* __restrict__ src,
                         const int* __restrict__ dst, const float* __restrict__ ew,
                         const float* __restrict__ als, const float* __restrict__ ald,
                         const float* __restrict__ de, float* __restrict__ exs) {
    int i = blockIdx.x * 256 + threadIdx.x;
    if (i >= N_EDGES) return;
    int e = edge_ids[i];
    int s = src[e], d = dst[e];
    float a = als[s] + ald[d] + ew[e] * de[HEADS];
    a = a > 0.f ? a : NEG_SLOPE * a;
    exs[i] = __expf(a);
}

// ---------------- fused layer-2 aggregation + bias ----------------

__global__ __launch_bounds__(256) void k_agg2(
        const float* __restrict__ xh2, const float* __restrict__ exs,
        const int* __restrict__ srcs, const int* __restrict__ row_ptr,
        const float* __restrict__ bias, float* __restrict__ out) {
    int node = blockIdx.x * 4 + (threadIdx.x >> 6);
    int lane = threadIdx.x & 63;
    int beg = row_ptr[node], end = row_ptr[node + 1];
    float acc = 0.f, den = 0.f;
    int i = beg;
    for (; i + 4 <= end; i += 4) {
        int s0 = srcs[i + 0], s1 = srcs[i + 1], s2 = srcs[i + 2], s3 = srcs[i + 3];
        float e0 = exs[i + 0], e1 = exs[i + 1], e2 = exs[i + 2], e3 = exs[i + 3];
        float x0 = xh2[(size_t)s0 * OUT_CH + lane];
        float x1 = xh2[(size_t)s1 * OUT_CH + lane];
        float x2 = xh2[(size_t)s2 * OUT_CH + lane];
        float x3 = xh2[(size_t)s3 * OUT_CH + lane];
        den += (e0 + e1) + (e2 + e3);
        acc = fmaf(e0, x0, fmaf(e1, x1, fmaf(e2, x2, fmaf(e3, x3, acc))));
    }
    for (; i < end; ++i) {
        int s = srcs[i];
        float e0 = exs[i];
        den += e0;
        acc = fmaf(e0, xh2[(size_t)s * OUT_CH + lane], acc);
    }
    out[(size_t)node * OUT_CH + lane] = acc / (den + 1e-16f) + bias[lane];
}

// ---------------- launch ----------------

extern "C" void kernel_launch(void* const* d_in, const int* in_sizes, int n_in,
                              void* d_out, int out_size, void* d_ws, size_t ws_size,
                              hipStream_t stream) {
    const float* x       = (const float*)d_in[0];
    const float* ew      = (const float*)d_in[1];
    const float* W1      = (const float*)d_in[2];
    const float* a_src1  = (const float*)d_in[3];
    const float* a_dst1  = (const float*)d_in[4];
    const float* a_edge1 = (const float*)d_in[5];
    const float* We1     = (const float*)d_in[6];
    const float* b1      = (const float*)d_in[7];
    const float* W2      = (const float*)d_in[8];
    const float* a_src2  = (const float*)d_in[9];
    const float* a_dst2  = (const float*)d_in[10];
    const float* a_edge2 = (const float*)d_in[11];
    const float* We2     = (const float*)d_in[12];
    const float* b2      = (const float*)d_in[13];
    const int*   eidx    = (const int*)d_in[14];
    const int* esrc = eidx;
    const int* edst = eidx + N_EDGES;
    float* out = (float*)d_out;

    char* p = (char*)d_ws;
    auto alloc = [&](size_t bytes) {
        char* r = p;
        p += (bytes + 255) & ~(size_t)255;
        return r;
    };
    float* xh1   = (float*)alloc((size_t)N_NODES * F1 * 4);
    float* h1    = (float*)alloc((size_t)N_NODES * F1 * 4);
    float* xh2   = (float*)alloc((size_t)N_NODES * OUT_CH * 4);
    float* als1  = (float*)alloc((size_t)N_NODES * HEADS * 4);
    float* ald1  = (float*)alloc((size_t)N_NODES * HEADS * 4);
    float* als2  = (float*)alloc((size_t)N_NODES * 4);
    float* ald2  = (float*)alloc((size_t)N_NODES * 4);
    float* de    = (float*)alloc(8 * 4);
    int* counts  = (int*)alloc((size_t)N_NODES * 4);
    int* cursor  = (int*)alloc((size_t)N_NODES * 4);
    int* row_ptr = (int*)alloc((size_t)(N_NODES + 1) * 4);
    int* edge_ids= (int*)alloc((size_t)N_EDGES * 4);
    float* exs1  = (float*)alloc((size_t)N_EDGES * 4 * 4);
    float* exs2  = (float*)alloc((size_t)N_EDGES * 4);
    int* srcs    = (int*)alloc((size_t)N_EDGES * 4);

    // CSR build
    k_zero2<<<(N_NODES + 255) / 256, 256, 0, stream>>>(counts, cursor);
    k_count<<<N_EDGES / 256, 256, 0, stream>>>(edst, counts);
    k_scan<<<1, 1024, 0, stream>>>(counts, row_ptr);
    k_fill<<<N_EDGES / 256, 256, 0, stream>>>(edst, row_ptr, cursor, edge_ids);
    k_de<<<1, 64, 0, stream>>>(We1, a_edge1, We2, a_edge2, de);

    // layer 1
    k_gemm1<<<(N_NODES + 31) / 32, 256, 0, stream>>>(x, W1, a_src1, a_dst1, xh1, als1, ald1);
    k_alpha1<<<N_EDGES / 256, 256, 0, stream>>>(edge_ids, esrc, edst, ew, als1, ald1, de,
                                                exs1, srcs);
    k_agg1<<<N_NODES / 4, 256, 0, stream>>>(xh1, exs1, srcs, row_ptr, b1, h1);

    // layer 2
    k_gemm2<<<(N_NODES + 31) / 32, 256, 0, stream>>>(h1, W2, a_src2, a_dst2, xh2, als2, ald2);
    k_alpha2<<<N_EDGES / 256, 256, 0, stream>>>(edge_ids, esrc, edst, ew, als2, ald2, de, exs2);
    k_agg2<<<N_NODES / 4, 256, 0, stream>>>(xh2, exs2, srcs, row_ptr, b2, out);
}